// Round 1
// baseline (517.115 us; speedup 1.0000x reference)
//
#include <hip/hip_runtime.h>
#include <hip/hip_bf16.h>
#include <math.h>

// Problem dims (fixed by reference)
#define BB 16
#define SS 2048
#define HH 512
#define AA 256
#define NCH 64          // chunks along t for the a-scan
#define CT  (SS/NCH)    // 32 tokens per chunk

// ---------------------------------------------------------------------------
// Kernel 1: e[tok] = sum_a q[a] * tanh( sum_h W[a,h] * x[tok,h] )
// Block: 256 threads, tile = 64 tokens x 256 a. LDS-staged fp32 GEMM.
// XOR swizzle on LDS columns keeps transposing stores 2-way (free) and
// b128 fragment reads conflict-free.
// ---------------------------------------------------------------------------
__global__ __launch_bounds__(256, 2) void gemm_e_kernel(
    const float* __restrict__ x, const float* __restrict__ W,
    const float* __restrict__ q, float* __restrict__ e)
{
    __shared__ float Wl[64][256];   // [h][a-swizzled]  64 KB
    __shared__ float Xl[64][64];    // [h][t-swizzled]  16 KB
    const int tid  = threadIdx.x;
    const int lane = tid & 63;      // a-group index (4 a's per lane)
    const int wv   = tid >> 6;      // wave id: 16 tokens per wave
    const long tok0 = (long)blockIdx.x * 64;

    float acc[4][16];
    #pragma unroll
    for (int i = 0; i < 4; i++)
        #pragma unroll
        for (int j = 0; j < 16; j++) acc[i][j] = 0.f;

    for (int hc = 0; hc < HH; hc += 64) {
        __syncthreads();
        // Stage W chunk [64 h x 256 a], transposed, swizzled.
        #pragma unroll
        for (int r = 0; r < 16; r++) {
            int idx = r * 256 + tid;          // 0..4095 float4s
            int a   = idx >> 4;               // 0..255
            int h4  = idx & 15;               // 0..15
            float4 v = *(const float4*)&W[(long)a * HH + hc + h4 * 4];
            int col = (((a >> 2) ^ (h4 & 7)) << 2) + (a & 3);
            int hh = h4 * 4;
            Wl[hh + 0][col] = v.x; Wl[hh + 1][col] = v.y;
            Wl[hh + 2][col] = v.z; Wl[hh + 3][col] = v.w;
        }
        // Stage x chunk [64 h x 64 t], transposed, swizzled.
        #pragma unroll
        for (int r = 0; r < 4; r++) {
            int idx = r * 256 + tid;          // 0..1023 float4s
            int t   = idx >> 4;               // 0..63
            int h4  = idx & 15;
            float4 v = *(const float4*)&x[(tok0 + t) * HH + hc + h4 * 4];
            int col = (((t >> 2) ^ (h4 & 7)) << 2) + (t & 3);
            int hh = h4 * 4;
            Xl[hh + 0][col] = v.x; Xl[hh + 1][col] = v.y;
            Xl[hh + 2][col] = v.z; Xl[hh + 3][col] = v.w;
        }
        __syncthreads();
        #pragma unroll 4
        for (int h = 0; h < 64; h++) {
            const int sh = (h >> 2) & 7;
            float4 wvv = *(const float4*)&Wl[h][(lane ^ sh) << 2];
            float xv[16];
            #pragma unroll
            for (int j4 = 0; j4 < 4; j4++) {
                float4 xx = *(const float4*)&Xl[h][(((wv << 2) + j4) ^ sh) << 2];
                xv[j4 * 4 + 0] = xx.x; xv[j4 * 4 + 1] = xx.y;
                xv[j4 * 4 + 2] = xx.z; xv[j4 * 4 + 3] = xx.w;
            }
            #pragma unroll
            for (int j = 0; j < 16; j++) {
                acc[0][j] = fmaf(wvv.x, xv[j], acc[0][j]);
                acc[1][j] = fmaf(wvv.y, xv[j], acc[1][j]);
                acc[2][j] = fmaf(wvv.z, xv[j], acc[2][j]);
                acc[3][j] = fmaf(wvv.w, xv[j], acc[3][j]);
            }
        }
    }
    // Epilogue: e contribution = q . tanh(acc), reduced over the 64 lanes (a dim)
    float4 qv = *(const float4*)&q[lane * 4];
    #pragma unroll
    for (int j = 0; j < 16; j++) {
        float sv = qv.x * tanhf(acc[0][j]) + qv.y * tanhf(acc[1][j])
                 + qv.z * tanhf(acc[2][j]) + qv.w * tanhf(acc[3][j]);
        #pragma unroll
        for (int off = 32; off > 0; off >>= 1) sv += __shfl_xor(sv, off, 64);
        if (lane == 0) e[tok0 + wv * 16 + j] = sv;
    }
}

// ---------------------------------------------------------------------------
// Kernel 2: per batch b: m = max_t e; w = exp(e-m); Z = inclusive prefix sum;
// store w and 1/Z. One block (256 thr) per b, 8 elements/thread.
// ---------------------------------------------------------------------------
__global__ __launch_bounds__(256) void softmax_scan_kernel(
    const float* __restrict__ e, float* __restrict__ w, float* __restrict__ zinv)
{
    __shared__ float red[256];
    const int b = blockIdx.x, tid = threadIdx.x;
    const float* eb = e + b * SS;
    float v[8];
    #pragma unroll
    for (int j = 0; j < 8; j++) v[j] = eb[tid * 8 + j];
    float m = v[0];
    #pragma unroll
    for (int j = 1; j < 8; j++) m = fmaxf(m, v[j]);
    red[tid] = m; __syncthreads();
    for (int st = 128; st > 0; st >>= 1) {
        if (tid < st) red[tid] = fmaxf(red[tid], red[tid + st]);
        __syncthreads();
    }
    const float mb = red[0];
    __syncthreads();
    float we[8], pf[8], p = 0.f;
    #pragma unroll
    for (int j = 0; j < 8; j++) { we[j] = expf(v[j] - mb); p += we[j]; pf[j] = p; }
    red[tid] = p; __syncthreads();
    // inclusive Hillis-Steele scan over 256 thread sums
    for (int st = 1; st < 256; st <<= 1) {
        float t = (tid >= st) ? red[tid - st] : 0.f;
        __syncthreads();
        red[tid] += t;
        __syncthreads();
    }
    const float excl = red[tid] - p;
    #pragma unroll
    for (int j = 0; j < 8; j++) {
        float Z = excl + pf[j];
        w[b * SS + tid * 8 + j]    = we[j];
        zinv[b * SS + tid * 8 + j] = 1.0f / Z;
    }
}

// ---------------------------------------------------------------------------
// Kernel 3: d[b,s,t] = (t<=s) ? w[b,t] * zinv[b,s] : 0.   One block per (b,s).
// Pure HBM-write-bound (268 MB).
// ---------------------------------------------------------------------------
__global__ __launch_bounds__(256) void write_d_kernel(
    const float* __restrict__ w, const float* __restrict__ zinv,
    float* __restrict__ dout)
{
    const int bs = blockIdx.x;
    const int b  = bs >> 11;
    const int s  = bs & (SS - 1);
    const float zi = zinv[bs];
    const float4* wb = (const float4*)(w + b * SS);
    float4* row = (float4*)(dout + (size_t)bs * SS);
    #pragma unroll
    for (int r = 0; r < 2; r++) {
        int t4 = r * 256 + threadIdx.x;
        int t  = t4 * 4;
        float4 wv = wb[t4];
        float4 o;
        o.x = (t + 0 <= s) ? wv.x * zi : 0.f;
        o.y = (t + 1 <= s) ? wv.y * zi : 0.f;
        o.z = (t + 2 <= s) ? wv.z * zi : 0.f;
        o.w = (t + 3 <= s) ? wv.w * zi : 0.f;
        row[t4] = o;
    }
}

// ---------------------------------------------------------------------------
// Kernel 4a: per-(b,chunk) partial sums  P[b,c,h] = sum_{t in chunk} w[b,t]*x[b,t,h]
// ---------------------------------------------------------------------------
__global__ __launch_bounds__(128) void scan_part_kernel(
    const float* __restrict__ x, const float* __restrict__ w, float* __restrict__ P)
{
    const int blk = blockIdx.x;
    const int b = blk >> 6;        // NCH = 64
    const int c = blk & 63;
    const int tid = threadIdx.x;   // h-float4 index 0..127
    const int t0 = c * CT;
    const float4* xb = (const float4*)(x + ((size_t)b * SS + t0) * HH);
    const float* wb = w + b * SS + t0;
    float4 acc = make_float4(0.f, 0.f, 0.f, 0.f);
    for (int t = 0; t < CT; t++) {
        float wt = wb[t];
        float4 xv = xb[(size_t)t * (HH / 4) + tid];
        acc.x = fmaf(wt, xv.x, acc.x);
        acc.y = fmaf(wt, xv.y, acc.y);
        acc.z = fmaf(wt, xv.z, acc.z);
        acc.w = fmaf(wt, xv.w, acc.w);
    }
    ((float4*)P)[(size_t)blk * (HH / 4) + tid] = acc;
}

// ---------------------------------------------------------------------------
// Kernel 4b: a[b,t,h] = (prefix_{t'<=t} w x) * zinv[b,t], seeded from chunk sums.
// ---------------------------------------------------------------------------
__global__ __launch_bounds__(128) void scan_emit_kernel(
    const float* __restrict__ x, const float* __restrict__ w,
    const float* __restrict__ zinv, const float* __restrict__ P,
    float* __restrict__ aout)
{
    const int blk = blockIdx.x;
    const int b = blk >> 6;
    const int c = blk & 63;
    const int tid = threadIdx.x;
    float4 base = make_float4(0.f, 0.f, 0.f, 0.f);
    for (int cc = 0; cc < c; cc++) {
        float4 p = ((const float4*)P)[(size_t)(b * NCH + cc) * (HH / 4) + tid];
        base.x += p.x; base.y += p.y; base.z += p.z; base.w += p.w;
    }
    const int t0 = c * CT;
    const float4* xb = (const float4*)(x + ((size_t)b * SS + t0) * HH);
    const float* wb = w + b * SS + t0;
    const float* zb = zinv + b * SS + t0;
    float4* ab = (float4*)(aout + ((size_t)b * SS + t0) * HH);
    for (int t = 0; t < CT; t++) {
        float wt = wb[t];
        float zi = zb[t];
        float4 xv = xb[(size_t)t * (HH / 4) + tid];
        base.x = fmaf(wt, xv.x, base.x);
        base.y = fmaf(wt, xv.y, base.y);
        base.z = fmaf(wt, xv.z, base.z);
        base.w = fmaf(wt, xv.w, base.w);
        float4 o = make_float4(base.x * zi, base.y * zi, base.z * zi, base.w * zi);
        ab[(size_t)t * (HH / 4) + tid] = o;
    }
}

extern "C" void kernel_launch(void* const* d_in, const int* in_sizes, int n_in,
                              void* d_out, int out_size, void* d_ws, size_t ws_size,
                              hipStream_t stream)
{
    const float* x = (const float*)d_in[0];   // [B,S,H]
    const float* W = (const float*)d_in[1];   // [A,H]
    const float* q = (const float*)d_in[2];   // [1,A]
    float* out  = (float*)d_out;
    float* aout = out;                         // [B,S,1,H]
    float* dout = out + (size_t)BB * SS * HH;  // [B,S,1,S]

    float* ws   = (float*)d_ws;
    float* e    = ws;                  // B*S
    float* w    = ws + BB * SS;        // B*S
    float* zinv = ws + 2 * BB * SS;    // B*S
    float* P    = ws + 3 * BB * SS;    // B*NCH*H  (2 MB)

    hipLaunchKernelGGL(gemm_e_kernel, dim3(BB * SS / 64), dim3(256), 0, stream,
                       x, W, q, e);
    hipLaunchKernelGGL(softmax_scan_kernel, dim3(BB), dim3(256), 0, stream,
                       e, w, zinv);
    hipLaunchKernelGGL(write_d_kernel, dim3(BB * SS), dim3(256), 0, stream,
                       w, zinv, dout);
    hipLaunchKernelGGL(scan_part_kernel, dim3(BB * NCH), dim3(128), 0, stream,
                       x, w, P);
    hipLaunchKernelGGL(scan_emit_kernel, dim3(BB * NCH), dim3(128), 0, stream,
                       x, w, zinv, P, aout);
}

// Round 3
// 433.014 us; speedup vs baseline: 1.1942x; 1.1942x over previous
//
#include <hip/hip_runtime.h>
#include <hip/hip_bf16.h>
#include <math.h>

// Problem dims (fixed by reference)
#define BB 16
#define SS 2048
#define HH 512
#define AA 256
#define NCH 128         // chunks along t for the a-scan
#define CT  (SS/NCH)    // 16 tokens per chunk
#define XST 72          // LDS row stride in bf16 (64 + 8 pad; 144B = 4 banks mod 32 -> 2-way free)

typedef short bf16x8 __attribute__((ext_vector_type(8)));
typedef float f32x4  __attribute__((ext_vector_type(4)));

__device__ __forceinline__ short f2bf(float f) {
    union { __hip_bfloat16 h; short s; } u;
    u.h = __float2bfloat16(f);
    return u.s;
}

__device__ __forceinline__ void nt_store4(float4 v, float4* p) {
    f32x4 o = {v.x, v.y, v.z, v.w};
    __builtin_nontemporal_store(o, (f32x4*)p);
}

// ---------------------------------------------------------------------------
// Kernel 0: W (fp32, [A,H]) -> bf16 once. 131072 elems, float4 per thread.
// ---------------------------------------------------------------------------
__global__ __launch_bounds__(256) void convW_kernel(
    const float* __restrict__ W, short* __restrict__ Wb)
{
    int i = blockIdx.x * 256 + threadIdx.x;      // float4 index, 32768 total
    float4 v = ((const float4*)W)[i];
    short4 o = make_short4(f2bf(v.x), f2bf(v.y), f2bf(v.z), f2bf(v.w));
    ((short4*)Wb)[i] = o;
}

// ---------------------------------------------------------------------------
// Kernel 1: e[tok] = sum_a q[a] * tanh( sum_h W[a,h]*x[tok,h] )  via bf16 MFMA.
// Block: 256 thr (4 waves, 2x2 wave grid), tile 64 tok x 256 a, BK=64.
// Each wave: 2 M-frags x 8 N-frags of mfma_f32_16x16x32_bf16.
// A-frag: A[m=lane&15][k=quad*8+j]; B-frag: B[k=quad*8+j][n=lane&15] (NT gemm,
// both frags read 8 contiguous k from their row). C/D: col=lane&15, row=quad*4+reg.
// ---------------------------------------------------------------------------
__global__ __launch_bounds__(256, 2) void gemm_e_mfma(
    const float* __restrict__ x, const short* __restrict__ Wb,
    const float* __restrict__ q, float* __restrict__ e)
{
    __shared__ short Xl[64 * XST];    //  9216 B
    __shared__ short Wl[256 * XST];   // 36864 B
    __shared__ float epart[2][64];

    const int tid  = threadIdx.x;
    const int lane = tid & 63;
    const int wv   = tid >> 6;
    const int wm   = wv & 1;          // token half (32 each)
    const int wn   = wv >> 1;         // a half (128 each)
    const int quad = lane >> 4;
    const int col  = lane & 15;
    const long tok0 = (long)blockIdx.x * 64;

    f32x4 acc[2][8];
    #pragma unroll
    for (int mt = 0; mt < 2; mt++)
        #pragma unroll
        for (int nt = 0; nt < 8; nt++) acc[mt][nt] = (f32x4){0.f, 0.f, 0.f, 0.f};

    for (int kc = 0; kc < HH; kc += 64) {
        __syncthreads();
        // Stage X: 64 tok x 64 k fp32 -> bf16. 512 segs of 8 floats, 2/thread.
        #pragma unroll
        for (int i = 0; i < 2; i++) {
            int task = i * 256 + tid;
            int row = task >> 3, seg = task & 7;
            const float* src = &x[(tok0 + row) * HH + kc + seg * 8];
            float4 v0 = *(const float4*)src;
            float4 v1 = *(const float4*)(src + 4);
            bf16x8 o;
            o[0] = f2bf(v0.x); o[1] = f2bf(v0.y); o[2] = f2bf(v0.z); o[3] = f2bf(v0.w);
            o[4] = f2bf(v1.x); o[5] = f2bf(v1.y); o[6] = f2bf(v1.z); o[7] = f2bf(v1.w);
            *(bf16x8*)&Xl[row * XST + seg * 8] = o;
        }
        // Stage W: 256 a x 64 k bf16 direct. 2048 segs of 8 bf16, 8/thread.
        #pragma unroll
        for (int i = 0; i < 8; i++) {
            int task = i * 256 + tid;
            int row = task >> 3, seg = task & 7;
            bf16x8 v = *(const bf16x8*)&Wb[row * HH + kc + seg * 8];
            *(bf16x8*)&Wl[row * XST + seg * 8] = v;
        }
        __syncthreads();
        #pragma unroll
        for (int kk = 0; kk < 64; kk += 32) {
            bf16x8 af[2], bfr[8];
            #pragma unroll
            for (int mt = 0; mt < 2; mt++)
                af[mt] = *(bf16x8*)&Xl[(wm * 32 + mt * 16 + col) * XST + kk + quad * 8];
            #pragma unroll
            for (int nt = 0; nt < 8; nt++)
                bfr[nt] = *(bf16x8*)&Wl[(wn * 128 + nt * 16 + col) * XST + kk + quad * 8];
            #pragma unroll
            for (int mt = 0; mt < 2; mt++)
                #pragma unroll
                for (int nt = 0; nt < 8; nt++)
                    acc[mt][nt] = __builtin_amdgcn_mfma_f32_16x16x32_bf16(
                        af[mt], bfr[nt], acc[mt][nt], 0, 0, 0);
        }
    }

    // Epilogue: e = q . tanh(act). Lane holds act[token=...quad*4+reg][a=...col].
    float qv[8];
    #pragma unroll
    for (int nt = 0; nt < 8; nt++) qv[nt] = q[wn * 128 + nt * 16 + col];
    #pragma unroll
    for (int mt = 0; mt < 2; mt++) {
        #pragma unroll
        for (int reg = 0; reg < 4; reg++) {
            float sv = 0.f;
            #pragma unroll
            for (int nt = 0; nt < 8; nt++) sv += qv[nt] * tanhf(acc[mt][nt][reg]);
            // reduce over the 16 cols (lanes within quad)
            #pragma unroll
            for (int off = 1; off < 16; off <<= 1) sv += __shfl_xor(sv, off, 64);
            if (col == 0)
                epart[wn][wm * 32 + mt * 16 + quad * 4 + reg] = sv;
        }
    }
    __syncthreads();
    if (tid < 64) e[tok0 + tid] = epart[0][tid] + epart[1][tid];
}

// ---------------------------------------------------------------------------
// Kernel 2: per batch b: m = max_t e; w = exp(e-m); Z = inclusive prefix; 1/Z.
// ---------------------------------------------------------------------------
__global__ __launch_bounds__(256) void softmax_scan_kernel(
    const float* __restrict__ e, float* __restrict__ w, float* __restrict__ zinv)
{
    __shared__ float red[256];
    const int b = blockIdx.x, tid = threadIdx.x;
    const float* eb = e + b * SS;
    float v[8];
    #pragma unroll
    for (int j = 0; j < 8; j++) v[j] = eb[tid * 8 + j];
    float m = v[0];
    #pragma unroll
    for (int j = 1; j < 8; j++) m = fmaxf(m, v[j]);
    red[tid] = m; __syncthreads();
    for (int st = 128; st > 0; st >>= 1) {
        if (tid < st) red[tid] = fmaxf(red[tid], red[tid + st]);
        __syncthreads();
    }
    const float mb = red[0];
    __syncthreads();
    float we[8], pf[8], p = 0.f;
    #pragma unroll
    for (int j = 0; j < 8; j++) { we[j] = expf(v[j] - mb); p += we[j]; pf[j] = p; }
    red[tid] = p; __syncthreads();
    for (int st = 1; st < 256; st <<= 1) {
        float t = (tid >= st) ? red[tid - st] : 0.f;
        __syncthreads();
        red[tid] += t;
        __syncthreads();
    }
    const float excl = red[tid] - p;
    #pragma unroll
    for (int j = 0; j < 8; j++) {
        float Z = excl + pf[j];
        w[b * SS + tid * 8 + j]    = we[j];
        zinv[b * SS + tid * 8 + j] = 1.0f / Z;
    }
}

// ---------------------------------------------------------------------------
// Kernel 3: d[b,s,t] = (t<=s) ? w[b,t]*zinv[b,s] : 0. One block per (b,s).
// Write-bound: 268 MB, nontemporal stores.
// ---------------------------------------------------------------------------
__global__ __launch_bounds__(256) void write_d_kernel(
    const float* __restrict__ w, const float* __restrict__ zinv,
    float* __restrict__ dout)
{
    const int bs = blockIdx.x;
    const int b  = bs >> 11;
    const int s  = bs & (SS - 1);
    const float zi = zinv[bs];
    const float4* wb = (const float4*)(w + b * SS);
    float4* row = (float4*)(dout + (size_t)bs * SS);
    #pragma unroll
    for (int r = 0; r < 2; r++) {
        int t4 = r * 256 + threadIdx.x;
        int t  = t4 * 4;
        float4 wv = wb[t4];
        float4 o;
        o.x = (t + 0 <= s) ? wv.x * zi : 0.f;
        o.y = (t + 1 <= s) ? wv.y * zi : 0.f;
        o.z = (t + 2 <= s) ? wv.z * zi : 0.f;
        o.w = (t + 3 <= s) ? wv.w * zi : 0.f;
        nt_store4(o, &row[t4]);
    }
}

// ---------------------------------------------------------------------------
// Kernel 4a: P[b,c,h] = sum_{t in chunk c} w[b,t]*x[b,t,h]
// ---------------------------------------------------------------------------
__global__ __launch_bounds__(128) void scan_part_kernel(
    const float* __restrict__ x, const float* __restrict__ w, float* __restrict__ P)
{
    const int blk = blockIdx.x;
    const int b = blk >> 7;        // NCH = 128
    const int c = blk & (NCH - 1);
    const int tid = threadIdx.x;   // h-float4 lane, 0..127
    const int t0 = c * CT;
    const float4* xb = (const float4*)(x + ((size_t)b * SS + t0) * HH);
    const float* wb = w + b * SS + t0;
    float4 acc = make_float4(0.f, 0.f, 0.f, 0.f);
    #pragma unroll 4
    for (int t = 0; t < CT; t++) {
        float wt = wb[t];
        float4 xv = xb[(size_t)t * (HH / 4) + tid];
        acc.x = fmaf(wt, xv.x, acc.x);
        acc.y = fmaf(wt, xv.y, acc.y);
        acc.z = fmaf(wt, xv.z, acc.z);
        acc.w = fmaf(wt, xv.w, acc.w);
    }
    ((float4*)P)[(size_t)blk * (HH / 4) + tid] = acc;
}

// ---------------------------------------------------------------------------
// Kernel 4b: in-place exclusive prefix over chunks: P[b,c,:] = sum_{c'<c} P_in.
// One block per b, thread owns one float4 column.
// ---------------------------------------------------------------------------
__global__ __launch_bounds__(128) void chunk_prefix_kernel(float* __restrict__ P)
{
    const int b = blockIdx.x, tid = threadIdx.x;
    float4* Pb = (float4*)P + (size_t)b * NCH * (HH / 4) + tid;
    float4 run = make_float4(0.f, 0.f, 0.f, 0.f);
    for (int c = 0; c < NCH; c += 4) {
        float4 p0 = Pb[(size_t)(c + 0) * (HH / 4)];
        float4 p1 = Pb[(size_t)(c + 1) * (HH / 4)];
        float4 p2 = Pb[(size_t)(c + 2) * (HH / 4)];
        float4 p3 = Pb[(size_t)(c + 3) * (HH / 4)];
        Pb[(size_t)(c + 0) * (HH / 4)] = run;
        run.x += p0.x; run.y += p0.y; run.z += p0.z; run.w += p0.w;
        Pb[(size_t)(c + 1) * (HH / 4)] = run;
        run.x += p1.x; run.y += p1.y; run.z += p1.z; run.w += p1.w;
        Pb[(size_t)(c + 2) * (HH / 4)] = run;
        run.x += p2.x; run.y += p2.y; run.z += p2.z; run.w += p2.w;
        Pb[(size_t)(c + 3) * (HH / 4)] = run;
        run.x += p3.x; run.y += p3.y; run.z += p3.z; run.w += p3.w;
    }
}

// ---------------------------------------------------------------------------
// Kernel 4c: a[b,t,h] = (base_c + prefix within chunk) * zinv[b,t]
// ---------------------------------------------------------------------------
__global__ __launch_bounds__(128) void scan_emit_kernel(
    const float* __restrict__ x, const float* __restrict__ w,
    const float* __restrict__ zinv, const float* __restrict__ P,
    float* __restrict__ aout)
{
    const int blk = blockIdx.x;
    const int b = blk >> 7;
    const int c = blk & (NCH - 1);
    const int tid = threadIdx.x;
    float4 base = ((const float4*)P)[(size_t)blk * (HH / 4) + tid];
    const int t0 = c * CT;
    const float4* xb = (const float4*)(x + ((size_t)b * SS + t0) * HH);
    const float* wb = w + b * SS + t0;
    const float* zb = zinv + b * SS + t0;
    float4* ab = (float4*)(aout + ((size_t)b * SS + t0) * HH);
    #pragma unroll 4
    for (int t = 0; t < CT; t++) {
        float wt = wb[t];
        float zi = zb[t];
        float4 xv = xb[(size_t)t * (HH / 4) + tid];
        base.x = fmaf(wt, xv.x, base.x);
        base.y = fmaf(wt, xv.y, base.y);
        base.z = fmaf(wt, xv.z, base.z);
        base.w = fmaf(wt, xv.w, base.w);
        float4 o = make_float4(base.x * zi, base.y * zi, base.z * zi, base.w * zi);
        nt_store4(o, &ab[(size_t)t * (HH / 4) + tid]);
    }
}

extern "C" void kernel_launch(void* const* d_in, const int* in_sizes, int n_in,
                              void* d_out, int out_size, void* d_ws, size_t ws_size,
                              hipStream_t stream)
{
    const float* x = (const float*)d_in[0];   // [B,S,H]
    const float* W = (const float*)d_in[1];   // [A,H]
    const float* q = (const float*)d_in[2];   // [1,A]
    float* out  = (float*)d_out;
    float* aout = out;                         // [B,S,1,H]
    float* dout = out + (size_t)BB * SS * HH;  // [B,S,1,S]

    float* ws   = (float*)d_ws;
    float* e    = ws;                           // B*S
    float* w    = ws + BB * SS;                 // B*S
    float* zinv = ws + 2 * BB * SS;             // B*S
    float* P    = ws + 3 * BB * SS;             // B*NCH*H = 4 MB
    short* Wb   = (short*)(ws + 3 * BB * SS + BB * NCH * HH);  // A*H bf16

    hipLaunchKernelGGL(convW_kernel, dim3(AA * HH / 4 / 256), dim3(256), 0, stream,
                       W, Wb);
    hipLaunchKernelGGL(gemm_e_mfma, dim3(BB * SS / 64), dim3(256), 0, stream,
                       x, Wb, q, e);
    hipLaunchKernelGGL(softmax_scan_kernel, dim3(BB), dim3(256), 0, stream,
                       e, w, zinv);
    hipLaunchKernelGGL(write_d_kernel, dim3(BB * SS), dim3(256), 0, stream,
                       w, zinv, dout);
    hipLaunchKernelGGL(scan_part_kernel, dim3(BB * NCH), dim3(128), 0, stream,
                       x, w, P);
    hipLaunchKernelGGL(chunk_prefix_kernel, dim3(BB), dim3(128), 0, stream,
                       P);
    hipLaunchKernelGGL(scan_emit_kernel, dim3(BB * NCH), dim3(128), 0, stream,
                       x, w, zinv, P, aout);
}